// Round 2
// baseline (681.441 us; speedup 1.0000x reference)
//
#include <hip/hip_runtime.h>
#include <math.h>

// Problem: B=64, S=2048, H=1024. Single-query attention + concat.
// out[b, 0:H]  = h_n[b]
// out[b, H:2H] = softmax_s(h_n[b]·enc[b,s,:]) @ enc[b,:,:]
//
// Memory-bound: enc is 536 MB; single-pass online softmax reads it once.
// R2: tile online softmax over T=4 rows to amortize the serial
// shuffle-reduce + exp + acc-rescale chain; 2048 blocks for more TLP.

#define BB 64
#define SS 2048
#define HH 1024
#define NCHUNK 32              // S-chunks per batch -> 64*32 = 2048 blocks
#define SCHUNK (SS / NCHUNK)   // 64 rows per block
#define NWAVE 4                // 256 threads
#define RPW (SCHUNK / NWAVE)   // 16 rows per wave
#define TT 4                   // rows per softmax tile
#define NTILE (RPW / TT)       // 4 tiles per wave

// ws layout:
//   [0 .. B*NCHUNK*H)            : partial ctx accumulators (float), 8.4 MB
//   [B*NCHUNK*H .. +B*NCHUNK*2)  : (m, l) pairs per partial
#define WS_ML_OFF ((size_t)BB * NCHUNK * HH)

__global__ __launch_bounds__(256) void attn_partial_kernel(
    const float* __restrict__ enc, const float* __restrict__ hn,
    float* __restrict__ ws)
{
    const int blk   = blockIdx.x;          // b * NCHUNK + chunk
    const int b     = blk / NCHUNK;
    const int chunk = blk % NCHUNK;
    const int tid   = threadIdx.x;
    const int wave  = tid >> 6;
    const int lane  = tid & 63;

    // Preload this lane's 16 h_n elements: float4 slot j*64+lane
    const float4* hn4 = (const float4*)(hn + (size_t)b * HH);
    float4 h4[4];
#pragma unroll
    for (int j = 0; j < 4; ++j) h4[j] = hn4[j * 64 + lane];

    const float4* enc4 = (const float4*)(enc + (size_t)b * SS * HH);

    float m = -INFINITY;
    float l = 0.0f;
    float4 acc[4];
#pragma unroll
    for (int j = 0; j < 4; ++j) acc[j] = make_float4(0.f, 0.f, 0.f, 0.f);

    // this wave's contiguous span of rows
    const int ws0 = chunk * SCHUNK + wave * RPW;

    for (int t = 0; t < NTILE; ++t) {
        const int sbase = ws0 + t * TT;

        // ---- load T=4 full rows into registers (64 independent loads/wave) ----
        float4 e[TT][4];
#pragma unroll
        for (int r = 0; r < TT; ++r) {
            const float4* row = enc4 + (size_t)(sbase + r) * (HH / 4);
#pragma unroll
            for (int j = 0; j < 4; ++j) e[r][j] = row[j * 64 + lane];
        }

        // ---- 4 independent dot products ----
        float d[TT];
#pragma unroll
        for (int r = 0; r < TT; ++r) {
            float s = 0.0f;
#pragma unroll
            for (int j = 0; j < 4; ++j) {
                s += e[r][j].x * h4[j].x + e[r][j].y * h4[j].y
                   + e[r][j].z * h4[j].z + e[r][j].w * h4[j].w;
            }
            d[r] = s;
        }

        // ---- batched butterfly reduce: 4 independent 6-step chains ----
#pragma unroll
        for (int off = 32; off > 0; off >>= 1) {
#pragma unroll
            for (int r = 0; r < TT; ++r)
                d[r] += __shfl_xor(d[r], off, 64);
        }

        // ---- one online-softmax update per tile ----
        float tmax = fmaxf(fmaxf(d[0], d[1]), fmaxf(d[2], d[3]));
        const float m_new = fmaxf(m, tmax);
        const float scale = __expf(m - m_new);   // first tile: exp(-inf)=0
        float p[TT];
        float psum = 0.0f;
#pragma unroll
        for (int r = 0; r < TT; ++r) {
            p[r] = __expf(d[r] - m_new);
            psum += p[r];
        }
        l = l * scale + psum;
#pragma unroll
        for (int j = 0; j < 4; ++j) {
            float x = acc[j].x * scale, y = acc[j].y * scale;
            float z = acc[j].z * scale, w = acc[j].w * scale;
#pragma unroll
            for (int r = 0; r < TT; ++r) {
                x += p[r] * e[r][j].x;  y += p[r] * e[r][j].y;
                z += p[r] * e[r][j].z;  w += p[r] * e[r][j].w;
            }
            acc[j] = make_float4(x, y, z, w);
        }
        m = m_new;
    }

    // ---- combine 4 wave-partials within the block via LDS ----
    __shared__ float s_m[NWAVE];
    __shared__ float s_l[NWAVE];
    __shared__ float s_acc[NWAVE][HH];     // 16 KB

#pragma unroll
    for (int j = 0; j < 4; ++j)
        ((float4*)s_acc[wave])[j * 64 + lane] = acc[j];
    if (lane == 0) { s_m[wave] = m; s_l[wave] = l; }
    __syncthreads();

    float M = fmaxf(fmaxf(s_m[0], s_m[1]), fmaxf(s_m[2], s_m[3]));
    float sc[NWAVE];
    float L = 0.0f;
#pragma unroll
    for (int w = 0; w < NWAVE; ++w) {
        sc[w] = __expf(s_m[w] - M);
        L += s_l[w] * sc[w];
    }

    // each thread finalizes one float4 slot (tid covers 256 slots = 1024 floats)
    float4 ctx = make_float4(0.f, 0.f, 0.f, 0.f);
#pragma unroll
    for (int w = 0; w < NWAVE; ++w) {
        float4 a = ((const float4*)s_acc[w])[tid];
        ctx.x += sc[w] * a.x;  ctx.y += sc[w] * a.y;
        ctx.z += sc[w] * a.z;  ctx.w += sc[w] * a.w;
    }
    ((float4*)(ws + (size_t)blk * HH))[tid] = ctx;
    if (tid == 0) {
        ws[WS_ML_OFF + (size_t)blk * 2 + 0] = M;
        ws[WS_ML_OFF + (size_t)blk * 2 + 1] = L;
    }
}

__global__ __launch_bounds__(256) void attn_final_kernel(
    const float* __restrict__ hn, const float* __restrict__ ws,
    float* __restrict__ out)
{
    const int b   = blockIdx.x;
    const int tid = threadIdx.x;
    const float* ml = ws + WS_ML_OFF + (size_t)b * NCHUNK * 2;

    float M = -INFINITY;
#pragma unroll
    for (int c = 0; c < NCHUNK; ++c) M = fmaxf(M, ml[c * 2]);

    float sc[NCHUNK];
    float T = 0.0f;
#pragma unroll
    for (int c = 0; c < NCHUNK; ++c) {
        sc[c] = __expf(ml[c * 2] - M);
        T += sc[c] * ml[c * 2 + 1];
    }
    const float invT = 1.0f / T;

    float4 ctx = make_float4(0.f, 0.f, 0.f, 0.f);
#pragma unroll
    for (int c = 0; c < NCHUNK; ++c) {
        float4 a = ((const float4*)(ws + (size_t)(b * NCHUNK + c) * HH))[tid];
        ctx.x += sc[c] * a.x;  ctx.y += sc[c] * a.y;
        ctx.z += sc[c] * a.z;  ctx.w += sc[c] * a.w;
    }
    ctx.x *= invT; ctx.y *= invT; ctx.z *= invT; ctx.w *= invT;

    const float4 dec = ((const float4*)(hn + (size_t)b * HH))[tid];
    float4* o = (float4*)(out + (size_t)b * 2 * HH);
    o[tid]            = dec;   // dec_output half
    o[tid + (HH / 4)] = ctx;   // context half
}

extern "C" void kernel_launch(void* const* d_in, const int* in_sizes, int n_in,
                              void* d_out, int out_size, void* d_ws, size_t ws_size,
                              hipStream_t stream) {
    const float* enc = (const float*)d_in[0];   // (B, S, H) fp32
    const float* hn  = (const float*)d_in[1];   // (B, H) fp32
    float* out = (float*)d_out;                 // (B, 1, 2H) fp32
    float* ws  = (float*)d_ws;

    attn_partial_kernel<<<dim3(BB * NCHUNK), dim3(256), 0, stream>>>(enc, hn, ws);
    attn_final_kernel<<<dim3(BB), dim3(256), 0, stream>>>(hn, ws, out);
}